// Round 10
// baseline (310.855 us; speedup 1.0000x reference)
//
#include <hip/hip_runtime.h>
#include <hip/hip_bf16.h>
#include <stdint.h>

#define KC   8      // mixture components
#define DIM  512    // obs dim
#define HID  512    // hidden
#define ACTN 1024   // actions
#define NS   64     // sequences
#define NT   128    // timesteps
#define NB   8192   // NS*NT
#define PB   8      // partial-lse blocks per row in GEMM2 (ACTN/128)

typedef __attribute__((ext_vector_type(8))) short short8;
typedef __attribute__((ext_vector_type(8))) unsigned short ushort8;
typedef __attribute__((ext_vector_type(4))) float floatx4;
typedef __attribute__((ext_vector_type(2))) float floatx2;
typedef __attribute__((ext_vector_type(4))) unsigned int uint4v;

__device__ inline float bf2f(unsigned short u) {
    return __uint_as_float(((unsigned int)u) << 16);
}
// cheap RNE f32->bf16 (no NaN handling needed for our data): 3 VALU ops
__device__ inline unsigned short f2bf_rne(float x) {
    unsigned int u = __float_as_uint(x);
    u += 0x7fffu + ((u >> 16) & 1u);
    return (unsigned short)(u >> 16);
}

// ---- fp8 e4m3fn encode/decode: HW packed converts (word-select is a
// compile-time template parameter), manual fallback ----
__device__ inline unsigned char f2fp8_manual(float v) {
    unsigned int s = (__float_as_uint(v) >> 24) & 0x80u;
    float a = fabsf(v) * 0x1.0p-120f;
    unsigned int b = __float_as_uint(a);
    b += 0x7FFFFu + ((b >> 20) & 1u);
    unsigned int m = b >> 20;
    if (m > 0x7Eu) m = 0x7Eu;
    return (unsigned char)(s | m);
}
__device__ inline float fp82f_manual(unsigned int byte) {
    unsigned int bits = ((byte & 0x80u) << 24) | ((byte & 0x7Fu) << 20);
    return __uint_as_float(bits) * 0x1.0p+120f;
}
template <bool HI>
__device__ inline unsigned int pk_fp8(float a, float b, unsigned int old) {
#if __has_builtin(__builtin_amdgcn_cvt_pk_fp8_f32)
    return __builtin_amdgcn_cvt_pk_fp8_f32(a, b, old, HI);
#else
    unsigned int p = (unsigned int)f2fp8_manual(a) | ((unsigned int)f2fp8_manual(b) << 8);
    return HI ? ((old & 0x0000ffffu) | (p << 16)) : ((old & 0xffff0000u) | p);
#endif
}
template <bool HI>
__device__ inline floatx2 unpk_fp8(unsigned int src) {
#if __has_builtin(__builtin_amdgcn_cvt_pk_f32_fp8)
    return __builtin_amdgcn_cvt_pk_f32_fp8(src, HI);
#else
    unsigned int w = HI ? (src >> 16) : src;
    floatx2 r;
    r.x = fp82f_manual(w & 0xffu);
    r.y = fp82f_manual((w >> 8) & 0xffu);
    return r;
#endif
}

// async global->LDS DMA, 16B/lane. GLOBAL address is PER-LANE (pass g + lane*8
// shorts); LDS dest = wave-uniform base + lane*16.
__device__ inline void gload_lds16(const unsigned short* g, unsigned short* l) {
    __builtin_amdgcn_global_load_lds(
        (const __attribute__((address_space(1))) unsigned int*)g,
        (__attribute__((address_space(3))) unsigned int*)l,
        16, 0, 0);
}

// ---------------- fused prep: obs->blocked bf16, W1/W2 -> blocked-transposed bf16 ----
// blocked layout: [rowgrp64][kchunk8][64 rows][8 bf16]  (1KB per [64][8] plane)
__global__ __launch_bounds__(256) void prep_kernel(
    const float* __restrict__ obs, const float* __restrict__ W1,
    const float* __restrict__ W2,
    unsigned short* __restrict__ obs_bk, unsigned short* __restrict__ W1bk,
    unsigned short* __restrict__ W2bk)
{
    __shared__ float tile[64][65];
    int id = blockIdx.x;
    if (id < 128) {                       // ---- obs path: [B][D] -> [B/64][D/8][64][8]
        int mg = id;
#pragma unroll
        for (int rep = 0; rep < 16; ++rep) {
            int idx = rep * 256 + threadIdx.x;   // 0..4095
            int kc  = idx >> 6;
            int row = idx & 63;
            const float* p = obs + ((size_t)(mg * 64 + row) * DIM) + kc * 8;
            ushort8 u;
#pragma unroll
            for (int e = 0; e < 8; e++) u[e] = f2bf_rne(p[e]);
            *(ushort8*)(obs_bk + (((size_t)mg * (DIM / 8) + kc) << 9) + (row << 3)) = u;
        }
        return;
    }
    // ---- weight transpose path: [z][R][C] -> [z][C/64][R/8][64][8]
    const float* src; unsigned short* dst; int R, C, xt, yt;
    if (id < 640) {                       // W1: 8 comps x (8 x 8) tiles
        int t = id - 128; int z = t >> 6; int rem = t & 63;
        xt = rem & 7; yt = rem >> 3;
        R = DIM; C = HID;
        src = W1 + (size_t)z * DIM * HID; dst = W1bk + (size_t)z * DIM * HID;
    } else {                              // W2: 8 comps x (16 x 8) tiles
        int t = id - 640; int z = t >> 7; int rem = t & 127;
        xt = rem & 15; yt = rem >> 4;
        R = HID; C = ACTN;
        src = W2 + (size_t)z * HID * ACTN; dst = W2bk + (size_t)z * HID * ACTN;
    }
    int h0 = xt * 64, d0 = yt * 64;
    int tx = threadIdx.x & 63, ty = threadIdx.x >> 6;
#pragma unroll
    for (int i = 0; i < 64; i += 4)
        tile[ty + i][tx] = src[(size_t)(d0 + ty + i) * C + h0 + tx];
    __syncthreads();
    int KCHR = R >> 3;
#pragma unroll
    for (int rep = 0; rep < 2; ++rep) {
        int idx  = rep * 256 + threadIdx.x;
        int h_l  = idx & 63;
        int dc_l = idx >> 6;
        ushort8 u;
#pragma unroll
        for (int e = 0; e < 8; e++) u[e] = f2bf_rne(tile[dc_l * 8 + e][h_l]);
        size_t off = ((((size_t)(h0 >> 6) * KCHR) + (d0 >> 3) + dc_l) << 9) + (h_l << 3);
        *(ushort8*)(dst + off) = u;
    }
}

// ---------------- batched bf16 MFMA GEMM on blocked operands, BK=64 ----------------
// A,B blocked [z][dim/64][Kd/8][64][8]. 2-barrier K-loop, 8 DMA issues/wave/iter.
// Two-half epilogue: Cs[64][136] (17.4 KB) keeps the LDS union at 32 KB ->
// 5 blocks/CU (vs 4), +25% co-resident waves to hide the barrier drain.
__global__ __launch_bounds__(256, 5) void gemm_blk_kernel(
    const unsigned short* __restrict__ Aall,
    const unsigned short* __restrict__ Ball,
    const float* __restrict__ biasall,
    void* __restrict__ Call,
    const int* __restrict__ actions,
    float* __restrict__ psum, float* __restrict__ palp,
    int M, int N, int Kd,
    long long zsA, long long zsB,
    int strideBias, long long strideCbytes,
    int do_relu, int do_lse, int do_blocked)
{
    // staging 32 KB (As/Bs: [8 planes][128 rows][8]); Cs [64][136] unions over it
    __shared__ __align__(16) unsigned short S[16384];
    unsigned short* const As = S;
    unsigned short* const Bs = S + 8192;

    const int zb = blockIdx.z;
    const float* bias = biasall + (size_t)zb * strideBias;
    char* const Cbase = (char*)Call + (size_t)zb * strideCbytes;

    const int tid  = threadIdx.x;
    const int lane = tid & 63;
    const int wave = tid >> 6;     // 0..3
    const int wm = wave >> 1;      // 0..1
    const int wn = wave & 1;       // 0..1
    const int quad = lane >> 4;    // 0..3 -> k-chunk within a 4-plane group
    const int l16  = lane & 15;

    const int bm = blockIdx.x * 128;
    const int bn = blockIdx.y * 128;
    const int KCH = Kd >> 3;

    floatx4 acc[4][4];
#pragma unroll
    for (int i = 0; i < 4; i++)
#pragma unroll
        for (int j = 0; j < 4; j++)
            acc[i][j] = (floatx4){0.f, 0.f, 0.f, 0.f};

    // wave w stages k-chunk planes {w, w+4}; per-lane contiguous 16B
    const int loff = lane << 3;
    const unsigned short* pA = Aall + (size_t)zb * zsA + (((size_t)(bm >> 6) * KCH + wave) << 9) + loff;
    const unsigned short* pB = Ball + (size_t)zb * zsB + (((size_t)(bn >> 6) * KCH + wave) << 9) + loff;
    const size_t mgs = (size_t)KCH << 9;   // next 64-row group
    unsigned short* ldsA = As + wave * 1024;
    unsigned short* ldsB = Bs + wave * 1024;

    const int nk = Kd >> 6;               // BK=64
    for (int it = 0; it < nk; ++it) {
        __syncthreads();                  // prev iter frag reads done
        gload_lds16(pA,              ldsA);          // plane w,   rows 0..63
        gload_lds16(pA + mgs,        ldsA + 512);    // plane w,   rows 64..127
        gload_lds16(pA + 2048,       ldsA + 4096);   // plane w+4, rows 0..63
        gload_lds16(pA + 2048 + mgs, ldsA + 4096 + 512);
        gload_lds16(pB,              ldsB);
        gload_lds16(pB + mgs,        ldsB + 512);
        gload_lds16(pB + 2048,       ldsB + 4096);
        gload_lds16(pB + 2048 + mgs, ldsB + 4096 + 512);
        pA += 4096; pB += 4096;           // advance 8 k-chunks
        __syncthreads();                  // vmcnt(0) drain before use

#pragma unroll
        for (int h = 0; h < 2; ++h) {     // h=0: planes 0..3, h=1: planes 4..7
            const unsigned short* Ah = As + h * 4096 + quad * 1024;
            const unsigned short* Bh = Bs + h * 4096 + quad * 1024;
            short8 af[4], bfr[4];
#pragma unroll
            for (int i = 0; i < 4; i++)
                af[i] = *(const short8*)(Ah + ((wm * 64 + i * 16 + l16) << 3));
#pragma unroll
            for (int j = 0; j < 4; j++)
                bfr[j] = *(const short8*)(Bh + ((wn * 64 + j * 16 + l16) << 3));
#pragma unroll
            for (int i = 0; i < 4; i++)
#pragma unroll
                for (int j = 0; j < 4; j++)
                    acc[i][j] = __builtin_amdgcn_mfma_f32_16x16x32_bf16(
                        af[i], bfr[j], acc[i][j], 0, 0, 0);
        }
    }
    __syncthreads();   // all frag reads done before Cs overwrite

    // ---- two-half epilogue: waves wm==hf write Cs[64][136]; all threads store ----
    // C/D layout (verified m89/m91): col = lane&15, row = quad*4 + reg.
    unsigned short* const Cs = S;
    for (int hf = 0; hf < 2; ++hf) {
        if (hf) __syncthreads();          // prev half's store reads done
        if (wm == hf) {
#pragma unroll
            for (int j = 0; j < 4; j++) {
                int col = wn * 64 + j * 16 + l16;
                float bv = bias[bn + col];
#pragma unroll
                for (int i = 0; i < 4; i++) {
                    int rwl = i * 16 + quad * 4;   // local row in half
#pragma unroll
                    for (int r = 0; r < 4; r++) {
                        float v = acc[i][j][r] + bv;
                        if (do_relu) v = fmaxf(v, 0.f);
                        Cs[(rwl + r) * 136 + col] = f2bf_rne(v);
                    }
                }
            }
        }
        __syncthreads();

        if (do_blocked) {
            // ---- blocked bf16 store: hbuf [z][M/64][N/8][64][8] ----
            unsigned short* Cb16 = (unsigned short*)Cbase;
            const int KCHo = N >> 3;
#pragma unroll
            for (int rep = 0; rep < 4; ++rep) {
                int idx   = rep * 256 + tid;     // 0..1023
                int kc_l  = idx >> 6;            // 0..15
                int row_l = idx & 63;            // 0..63
                int row   = hf * 64 + row_l;
                ushort8 u = *(const ushort8*)&Cs[row_l * 136 + kc_l * 8];
                size_t off = ((((size_t)((bm >> 6) + (row >> 6)) * KCHo) + (bn >> 3) + kc_l) << 9)
                           + ((row & 63) << 3);
                *(ushort8*)(Cb16 + off) = u;     // consecutive lanes -> 1KB runs
            }
        } else {
            // ---- row-major fp8 store + fused exp-sum / action gather ----
            unsigned char* Cb8 = (unsigned char*)Cbase;
            const int row_l = tid >> 2;          // 0..63
            const int ch    = (tid & 3) * 32;    // 32-col slice
            const int browg = bm + hf * 64 + row_l;
            unsigned char* crow = Cb8 + (size_t)browg * N + bn + ch;

            float s = 0.f;
#pragma unroll
            for (int g = 0; g < 2; g++) {        // 16 els -> one 16B store
                ushort8 u0 = *(const ushort8*)&Cs[row_l * 136 + ch + 16 * g];
                ushort8 u1 = *(const ushort8*)&Cs[row_l * 136 + ch + 16 * g + 8];
                float v[16];
#pragma unroll
                for (int e = 0; e < 8; e++) { v[e] = bf2f(u0[e]); v[8 + e] = bf2f(u1[e]); }
#pragma unroll
                for (int e = 0; e < 16; e++) s += __expf(v[e]);
                uint4v pk;
                pk.x = pk_fp8<true>(v[2],  v[3],  pk_fp8<false>(v[0],  v[1],  0u));
                pk.y = pk_fp8<true>(v[6],  v[7],  pk_fp8<false>(v[4],  v[5],  0u));
                pk.z = pk_fp8<true>(v[10], v[11], pk_fp8<false>(v[8],  v[9],  0u));
                pk.w = pk_fp8<true>(v[14], v[15], pk_fp8<false>(v[12], v[13], 0u));
                *(uint4v*)(crow + 16 * g) = pk;
            }

            s += __shfl_xor(s, 1);
            s += __shfl_xor(s, 2);
            size_t kb = (size_t)zb * M + browg;  // M == NB for GEMM2
            if ((tid & 3) == 0)
                psum[kb * PB + blockIdx.y] = s;
            int act = actions[browg];
            int rel = act - bn;
            if (rel >= ch && rel < ch + 32)
                palp[kb] = bf2f(Cs[row_l * 136 + rel]);   // bf16-accurate action logit
        }
    }
}

// ---------------- per-sequence: lse-finish + scan + mixture posterior ----------------
__global__ __launch_bounds__(128) void mix_kernel(
    const float* __restrict__ palp,   // [K][B]  raw action logit (bf16 acc)
    const float* __restrict__ psum,   // [K][B][PB]  raw exp-sums
    const float* __restrict__ start,  // [S][K]
    float* __restrict__ w,            // [K][B]  = mix - lse
    float* __restrict__ fmix)         // [S][K]
{
    __shared__ float buf[2][NT][9];
    int s = blockIdx.x, t = threadIdx.x;
    int b = s * NT + t;

    float a[KC], lsev[KC];
#pragma unroll
    for (int k = 0; k < KC; k++) {
        size_t kb = (size_t)k * NB + b;
        const float* ps = psum + kb * PB;
        float S = 0.f;
#pragma unroll
        for (int p = 0; p < PB; p++) S += ps[p];
        float l = __logf(S);
        lsev[k] = l;
        a[k] = palp[kb] - l;          // action logprob
    }

#pragma unroll
    for (int k = 0; k < KC; k++) buf[0][t][k] = a[k];
    int p = 0;
    for (int off = 1; off < NT; off <<= 1) {
        __syncthreads();
#pragma unroll
        for (int k = 0; k < KC; k++) {
            float x = buf[p][t][k];
            if (t >= off) x += buf[p][t - off][k];
            buf[1 - p][t][k] = x;
        }
        p ^= 1;
    }
    __syncthreads();
    float st[KC], e[KC];
#pragma unroll
    for (int k = 0; k < KC; k++) st[k] = start[s * KC + k];
#pragma unroll
    for (int k = 0; k < KC; k++) e[k] = st[k] + buf[p][t][k] - a[k];  // exclusive cumsum
    float m = e[0];
#pragma unroll
    for (int k = 1; k < KC; k++) m = fmaxf(m, e[k]);
    float sum = 0.f;
#pragma unroll
    for (int k = 0; k < KC; k++) sum += __expf(e[k] - m);
    float l = m + __logf(sum);
#pragma unroll
    for (int k = 0; k < KC; k++)
        w[(size_t)k * NB + b] = (e[k] - l) - lsev[k];

    if (t == NT - 1) {
        float f[KC];
#pragma unroll
        for (int k = 0; k < KC; k++) f[k] = st[k] + buf[p][t][k];
        float m2 = f[0];
#pragma unroll
        for (int k = 1; k < KC; k++) m2 = fmaxf(m2, f[k]);
        float s2 = 0.f;
#pragma unroll
        for (int k = 0; k < KC; k++) s2 += __expf(f[k] - m2);
        float l2 = m2 + __logf(s2);
#pragma unroll
        for (int k = 0; k < KC; k++) fmix[s * KC + k] = f[k] - l2;
    }
}

// ---------------- final combine: out[b,a] = LSE_k(logit8[k,b,a] + w[k,b]) ----------------
__global__ __launch_bounds__(256) void combine_kernel(
    const unsigned char* __restrict__ logits8,  // [K][B][A] fp8 e4m3
    const float* __restrict__ w,                // [K][B]
    float* __restrict__ out)                    // [B][A]
{
    int b  = blockIdx.x * 2 + (threadIdx.x >> 7);
    int a0 = (threadIdx.x & 127) * 8;
    float x[KC][8];
#pragma unroll
    for (int k = 0; k < KC; k++) {
        float wv = w[(size_t)k * NB + b];
        uint2 q = *(const uint2*)(logits8 + ((size_t)k * NB + b) * ACTN + a0);
        floatx2 p01 = unpk_fp8<false>(q.x), p23 = unpk_fp8<true>(q.x);
        floatx2 p45 = unpk_fp8<false>(q.y), p67 = unpk_fp8<true>(q.y);
        x[k][0] = p01.x + wv; x[k][1] = p01.y + wv;
        x[k][2] = p23.x + wv; x[k][3] = p23.y + wv;
        x[k][4] = p45.x + wv; x[k][5] = p45.y + wv;
        x[k][6] = p67.x + wv; x[k][7] = p67.y + wv;
    }
    float* op = out + (size_t)b * ACTN + a0;
#pragma unroll
    for (int j = 0; j < 8; j++) {
        float m = x[0][j];
#pragma unroll
        for (int k = 1; k < KC; k++) m = fmaxf(m, x[k][j]);
        float s = 0.f;
#pragma unroll
        for (int k = 0; k < KC; k++) s += __expf(x[k][j] - m);
        op[j] = m + __logf(s);
    }
}

extern "C" void kernel_launch(void* const* d_in, const int* in_sizes, int n_in,
                              void* d_out, int out_size, void* d_ws, size_t ws_size,
                              hipStream_t stream)
{
    const float* obs     = (const float*)d_in[0];
    const int*   actions = (const int*)d_in[1];
    const float* start   = (const float*)d_in[2];
    const float* W1      = (const float*)d_in[3];
    const float* b1      = (const float*)d_in[4];
    const float* W2      = (const float*)d_in[5];
    const float* b2      = (const float*)d_in[6];
    // d_in[7] = seq_len (compile-time NT)

    char* ws = (char*)d_ws;
    unsigned short* obs_bk  = (unsigned short*)ws; ws += (size_t)NB * DIM * 2;        // 8 MB
    unsigned short* W1bk    = (unsigned short*)ws; ws += (size_t)KC * HID * DIM * 2;  // 4 MB
    unsigned short* W2bk    = (unsigned short*)ws; ws += (size_t)KC * ACTN * HID * 2; // 8 MB
    unsigned short* hbuf    = (unsigned short*)ws; ws += (size_t)KC * NB * HID * 2;   // 64 MB
    unsigned char*  logits8 = (unsigned char*)ws;  ws += (size_t)KC * NB * ACTN;      // 64 MB
    float* wbuf = (float*)ws; ws += (size_t)KC * NB * 4;                              // 256 KB
    float* psum = (float*)ws; ws += (size_t)KC * NB * PB * 4;                         // 2 MB
    float* palp = (float*)ws; ws += (size_t)KC * NB * 4;                              // 256 KB

    float* out  = (float*)d_out;
    float* fmix = out + (size_t)NB * ACTN;

    // 1. fused prep: obs + W1 + W2 -> blocked bf16
    prep_kernel<<<1664, 256, 0, stream>>>(obs, W1, W2, obs_bk, W1bk, W2bk);

    // 2. h = relu(obs @ W1[k] + b1[k]) -> blocked bf16 (zsA=0: obs shared!)
    gemm_blk_kernel<<<dim3(NB / 128, HID / 128, KC), 256, 0, stream>>>(
        obs_bk, W1bk, b1, hbuf, actions, psum, palp,
        NB, HID, DIM,
        0LL, (long long)HID * DIM,
        HID, (long long)NB * HID * 2, 1, 0, 1);

    // 3. logits = h @ W2[k] + b2[k] -> fp8 [K][B][A] + fused exp-sum + gather
    gemm_blk_kernel<<<dim3(NB / 128, ACTN / 128, KC), 256, 0, stream>>>(
        hbuf, W2bk, b2, logits8, actions, psum, palp,
        NB, ACTN, HID,
        (long long)NB * HID, (long long)ACTN * HID,
        ACTN, (long long)NB * ACTN, 0, 1, 0);

    // 4. per-sequence: lse-finish + cumsum scan -> mixture weights + final mixture logprobs
    mix_kernel<<<NS, NT, 0, stream>>>(palp, psum, start, wbuf, fmix);

    // 5. combine over components
    combine_kernel<<<NB / 2, 256, 0, stream>>>(logits8, wbuf, out);
}

// Round 11
// 258.166 us; speedup vs baseline: 1.2041x; 1.2041x over previous
//
#include <hip/hip_runtime.h>
#include <hip/hip_bf16.h>
#include <stdint.h>

#define KC   8      // mixture components
#define DIM  512    // obs dim
#define HID  512    // hidden
#define ACTN 1024   // actions
#define NS   64     // sequences
#define NT   128    // timesteps
#define NB   8192   // NS*NT
#define PB   8      // partial-lse blocks per row in GEMM2 (ACTN/128)

typedef __attribute__((ext_vector_type(8))) short short8;
typedef __attribute__((ext_vector_type(8))) unsigned short ushort8;
typedef __attribute__((ext_vector_type(4))) float floatx4;
typedef __attribute__((ext_vector_type(2))) float floatx2;
typedef __attribute__((ext_vector_type(4))) unsigned int uint4v;

__device__ inline float bf2f(unsigned short u) {
    return __uint_as_float(((unsigned int)u) << 16);
}
// cheap RNE f32->bf16 (no NaN handling needed for our data): 3 VALU ops
__device__ inline unsigned short f2bf_rne(float x) {
    unsigned int u = __float_as_uint(x);
    u += 0x7fffu + ((u >> 16) & 1u);
    return (unsigned short)(u >> 16);
}

// ---- fp8 e4m3fn encode/decode: HW packed converts (word-select is a
// compile-time template parameter), manual fallback ----
__device__ inline unsigned char f2fp8_manual(float v) {
    unsigned int s = (__float_as_uint(v) >> 24) & 0x80u;
    float a = fabsf(v) * 0x1.0p-120f;
    unsigned int b = __float_as_uint(a);
    b += 0x7FFFFu + ((b >> 20) & 1u);
    unsigned int m = b >> 20;
    if (m > 0x7Eu) m = 0x7Eu;
    return (unsigned char)(s | m);
}
__device__ inline float fp82f_manual(unsigned int byte) {
    unsigned int bits = ((byte & 0x80u) << 24) | ((byte & 0x7Fu) << 20);
    return __uint_as_float(bits) * 0x1.0p+120f;
}
template <bool HI>
__device__ inline unsigned int pk_fp8(float a, float b, unsigned int old) {
#if __has_builtin(__builtin_amdgcn_cvt_pk_fp8_f32)
    return __builtin_amdgcn_cvt_pk_fp8_f32(a, b, old, HI);
#else
    unsigned int p = (unsigned int)f2fp8_manual(a) | ((unsigned int)f2fp8_manual(b) << 8);
    return HI ? ((old & 0x0000ffffu) | (p << 16)) : ((old & 0xffff0000u) | p);
#endif
}
template <bool HI>
__device__ inline floatx2 unpk_fp8(unsigned int src) {
#if __has_builtin(__builtin_amdgcn_cvt_pk_f32_fp8)
    return __builtin_amdgcn_cvt_pk_f32_fp8(src, HI);
#else
    unsigned int w = HI ? (src >> 16) : src;
    floatx2 r;
    r.x = fp82f_manual(w & 0xffu);
    r.y = fp82f_manual((w >> 8) & 0xffu);
    return r;
#endif
}

// async global->LDS DMA, 16B/lane. GLOBAL address is PER-LANE (pass g + lane*8
// shorts); LDS dest = wave-uniform base + lane*16.
__device__ inline void gload_lds16(const unsigned short* g, unsigned short* l) {
    __builtin_amdgcn_global_load_lds(
        (const __attribute__((address_space(1))) unsigned int*)g,
        (__attribute__((address_space(3))) unsigned int*)l,
        16, 0, 0);
}

// ---------------- fused prep: obs->blocked bf16, W1/W2 -> blocked-transposed bf16 ----
// blocked layout: [rowgrp64][kchunk8][64 rows][8 bf16]  (1KB per [64][8] plane)
__global__ __launch_bounds__(256) void prep_kernel(
    const float* __restrict__ obs, const float* __restrict__ W1,
    const float* __restrict__ W2,
    unsigned short* __restrict__ obs_bk, unsigned short* __restrict__ W1bk,
    unsigned short* __restrict__ W2bk)
{
    __shared__ float tile[64][65];
    int id = blockIdx.x;
    if (id < 128) {                       // ---- obs path: [B][D] -> [B/64][D/8][64][8]
        int mg = id;
#pragma unroll
        for (int rep = 0; rep < 16; ++rep) {
            int idx = rep * 256 + threadIdx.x;   // 0..4095
            int kc  = idx >> 6;
            int row = idx & 63;
            const float* p = obs + ((size_t)(mg * 64 + row) * DIM) + kc * 8;
            ushort8 u;
#pragma unroll
            for (int e = 0; e < 8; e++) u[e] = f2bf_rne(p[e]);
            *(ushort8*)(obs_bk + (((size_t)mg * (DIM / 8) + kc) << 9) + (row << 3)) = u;
        }
        return;
    }
    // ---- weight transpose path: [z][R][C] -> [z][C/64][R/8][64][8]
    const float* src; unsigned short* dst; int R, C, xt, yt;
    if (id < 640) {                       // W1: 8 comps x (8 x 8) tiles
        int t = id - 128; int z = t >> 6; int rem = t & 63;
        xt = rem & 7; yt = rem >> 3;
        R = DIM; C = HID;
        src = W1 + (size_t)z * DIM * HID; dst = W1bk + (size_t)z * DIM * HID;
    } else {                              // W2: 8 comps x (16 x 8) tiles
        int t = id - 640; int z = t >> 7; int rem = t & 127;
        xt = rem & 15; yt = rem >> 4;
        R = HID; C = ACTN;
        src = W2 + (size_t)z * HID * ACTN; dst = W2bk + (size_t)z * HID * ACTN;
    }
    int h0 = xt * 64, d0 = yt * 64;
    int tx = threadIdx.x & 63, ty = threadIdx.x >> 6;
#pragma unroll
    for (int i = 0; i < 64; i += 4)
        tile[ty + i][tx] = src[(size_t)(d0 + ty + i) * C + h0 + tx];
    __syncthreads();
    int KCHR = R >> 3;
#pragma unroll
    for (int rep = 0; rep < 2; ++rep) {
        int idx  = rep * 256 + threadIdx.x;
        int h_l  = idx & 63;
        int dc_l = idx >> 6;
        ushort8 u;
#pragma unroll
        for (int e = 0; e < 8; e++) u[e] = f2bf_rne(tile[dc_l * 8 + e][h_l]);
        size_t off = ((((size_t)(h0 >> 6) * KCHR) + (d0 >> 3) + dc_l) << 9) + (h_l << 3);
        *(ushort8*)(dst + off) = u;
    }
}

// ---------------- batched bf16 MFMA GEMM on blocked operands, BK=64 ----------------
// A,B blocked [z][dim/64][Kd/8][64][8]. 2-barrier K-loop, 8 DMA issues/wave/iter.
// zsA=0 when A shared across components (obs).
// NOTE: occupancy 4 blocks/CU is the max — acc[4][4] (64 regs, unified VGPR/AGPR
// file) + ~60 addressing regs ≈ 124; forcing 5 waves/EU (cap 102) spills to
// scratch inside the K-loop (round 10: WRITE 69->205 MB, 90->124 µs).
__global__ __launch_bounds__(256, 4) void gemm_blk_kernel(
    const unsigned short* __restrict__ Aall,
    const unsigned short* __restrict__ Ball,
    const float* __restrict__ biasall,
    void* __restrict__ Call,
    const int* __restrict__ actions,
    float* __restrict__ psum, float* __restrict__ palp,
    int M, int N, int Kd,
    long long zsA, long long zsB,
    int strideBias, long long strideCbytes,
    int do_relu, int do_lse, int do_blocked)
{
    // staging 32 KB (As/Bs: [8 planes][128 rows][8]); Cs [128][136] (34816 B) unions over it
    __shared__ __align__(16) unsigned short S[17408];
    unsigned short* const As = S;
    unsigned short* const Bs = S + 8192;

    const int zb = blockIdx.z;
    const float* bias = biasall + (size_t)zb * strideBias;
    char* const Cbase = (char*)Call + (size_t)zb * strideCbytes;

    const int tid  = threadIdx.x;
    const int lane = tid & 63;
    const int wave = tid >> 6;     // 0..3
    const int wm = wave >> 1;      // 0..1
    const int wn = wave & 1;       // 0..1
    const int quad = lane >> 4;    // 0..3 -> k-chunk within a 4-plane group
    const int l16  = lane & 15;

    const int bm = blockIdx.x * 128;
    const int bn = blockIdx.y * 128;
    const int KCH = Kd >> 3;

    floatx4 acc[4][4];
#pragma unroll
    for (int i = 0; i < 4; i++)
#pragma unroll
        for (int j = 0; j < 4; j++)
            acc[i][j] = (floatx4){0.f, 0.f, 0.f, 0.f};

    // wave w stages k-chunk planes {w, w+4}; per-lane contiguous 16B
    const int loff = lane << 3;
    const unsigned short* pA = Aall + (size_t)zb * zsA + (((size_t)(bm >> 6) * KCH + wave) << 9) + loff;
    const unsigned short* pB = Ball + (size_t)zb * zsB + (((size_t)(bn >> 6) * KCH + wave) << 9) + loff;
    const size_t mgs = (size_t)KCH << 9;   // next 64-row group
    unsigned short* ldsA = As + wave * 1024;
    unsigned short* ldsB = Bs + wave * 1024;

    const int nk = Kd >> 6;               // BK=64
    for (int it = 0; it < nk; ++it) {
        __syncthreads();                  // prev iter frag reads done
        gload_lds16(pA,              ldsA);          // plane w,   rows 0..63
        gload_lds16(pA + mgs,        ldsA + 512);    // plane w,   rows 64..127
        gload_lds16(pA + 2048,       ldsA + 4096);   // plane w+4, rows 0..63
        gload_lds16(pA + 2048 + mgs, ldsA + 4096 + 512);
        gload_lds16(pB,              ldsB);
        gload_lds16(pB + mgs,        ldsB + 512);
        gload_lds16(pB + 2048,       ldsB + 4096);
        gload_lds16(pB + 2048 + mgs, ldsB + 4096 + 512);
        pA += 4096; pB += 4096;           // advance 8 k-chunks
        __syncthreads();                  // vmcnt(0) drain before use

#pragma unroll
        for (int h = 0; h < 2; ++h) {     // h=0: planes 0..3, h=1: planes 4..7
            const unsigned short* Ah = As + h * 4096 + quad * 1024;
            const unsigned short* Bh = Bs + h * 4096 + quad * 1024;
            short8 af[4], bfr[4];
#pragma unroll
            for (int i = 0; i < 4; i++)
                af[i] = *(const short8*)(Ah + ((wm * 64 + i * 16 + l16) << 3));
#pragma unroll
            for (int j = 0; j < 4; j++)
                bfr[j] = *(const short8*)(Bh + ((wn * 64 + j * 16 + l16) << 3));
#pragma unroll
            for (int i = 0; i < 4; i++)
#pragma unroll
                for (int j = 0; j < 4; j++)
                    acc[i][j] = __builtin_amdgcn_mfma_f32_16x16x32_bf16(
                        af[i], bfr[j], acc[i][j], 0, 0, 0);
        }
    }
    __syncthreads();   // all frag reads done before Cs overwrite

    // ---- epilogue: acc -> LDS C-tile (bf16, bias+relu applied) ----
    // C/D layout (verified m89/m91): col = lane&15, row = quad*4 + reg.
    unsigned short* const Cs = S;
#pragma unroll
    for (int j = 0; j < 4; j++) {
        int col = wn * 64 + j * 16 + l16;
        float bv = bias[bn + col];
#pragma unroll
        for (int i = 0; i < 4; i++) {
            int rw = wm * 64 + i * 16 + quad * 4;
#pragma unroll
            for (int r = 0; r < 4; r++) {
                float v = acc[i][j][r] + bv;
                if (do_relu) v = fmaxf(v, 0.f);
                Cs[(rw + r) * 136 + col] = f2bf_rne(v);
            }
        }
    }
    __syncthreads();

    if (do_blocked) {
        // ---- blocked bf16 store: hbuf [z][M/64][N/8][64][8] (= GEMM2's A layout) ----
        unsigned short* Cb16 = (unsigned short*)Cbase;
        const int KCHo = N >> 3;
#pragma unroll
        for (int rep = 0; rep < 8; ++rep) {
            int idx  = rep * 256 + tid;      // 0..2047
            int kc_l = idx >> 7;             // 0..15
            int row  = idx & 127;
            ushort8 u = *(const ushort8*)&Cs[row * 136 + kc_l * 8];
            size_t off = ((((size_t)((bm >> 6) + (row >> 6)) * KCHo) + (bn >> 3) + kc_l) << 9)
                       + ((row & 63) << 3);
            *(ushort8*)(Cb16 + off) = u;     // consecutive lanes -> 1KB runs
        }
    } else {
        // ---- row-major fp8 store + fused exp-sum / action gather (no max pass:
        //      |logit| < ~4, raw exp is fp32-safe) ----
        unsigned char* Cb8 = (unsigned char*)Cbase;
        const int row = tid >> 1;
        const int ch  = (tid & 1) * 64;
        unsigned char* crow = Cb8 + (size_t)(bm + row) * N + bn + ch;

        float s = 0.f;
#pragma unroll
        for (int g = 0; g < 4; g++) {        // 16 els -> one 16B store
            ushort8 u0 = *(const ushort8*)&Cs[row * 136 + ch + 16 * g];
            ushort8 u1 = *(const ushort8*)&Cs[row * 136 + ch + 16 * g + 8];
            float v[16];
#pragma unroll
            for (int e = 0; e < 8; e++) { v[e] = bf2f(u0[e]); v[8 + e] = bf2f(u1[e]); }
#pragma unroll
            for (int e = 0; e < 16; e++) s += __expf(v[e]);
            uint4v pk;
            pk.x = pk_fp8<true>(v[2],  v[3],  pk_fp8<false>(v[0],  v[1],  0u));
            pk.y = pk_fp8<true>(v[6],  v[7],  pk_fp8<false>(v[4],  v[5],  0u));
            pk.z = pk_fp8<true>(v[10], v[11], pk_fp8<false>(v[8],  v[9],  0u));
            pk.w = pk_fp8<true>(v[14], v[15], pk_fp8<false>(v[12], v[13], 0u));
            *(uint4v*)(crow + 16 * g) = pk;
        }

        float stot = s + __shfl_xor(s, 1);
        size_t kb = (size_t)zb * M + bm + row;   // M == NB for GEMM2
        if ((tid & 1) == 0)
            psum[kb * PB + blockIdx.y] = stot;
        int act = actions[bm + row];
        int rel = act - bn;
        if (rel >= ch && rel < ch + 64)
            palp[kb] = bf2f(Cs[row * 136 + rel]);   // bf16-accurate action logit
    }
}

// ---------------- per-sequence: lse-finish + scan + mixture posterior ----------------
__global__ __launch_bounds__(128) void mix_kernel(
    const float* __restrict__ palp,   // [K][B]  raw action logit (bf16 acc)
    const float* __restrict__ psum,   // [K][B][PB]  raw exp-sums
    const float* __restrict__ start,  // [S][K]
    float* __restrict__ w,            // [K][B]  = mix - lse
    float* __restrict__ fmix)         // [S][K]
{
    __shared__ float buf[2][NT][9];
    int s = blockIdx.x, t = threadIdx.x;
    int b = s * NT + t;

    float a[KC], lsev[KC];
#pragma unroll
    for (int k = 0; k < KC; k++) {
        size_t kb = (size_t)k * NB + b;
        const float* ps = psum + kb * PB;
        float S = 0.f;
#pragma unroll
        for (int p = 0; p < PB; p++) S += ps[p];
        float l = __logf(S);
        lsev[k] = l;
        a[k] = palp[kb] - l;          // action logprob
    }

#pragma unroll
    for (int k = 0; k < KC; k++) buf[0][t][k] = a[k];
    int p = 0;
    for (int off = 1; off < NT; off <<= 1) {
        __syncthreads();
#pragma unroll
        for (int k = 0; k < KC; k++) {
            float x = buf[p][t][k];
            if (t >= off) x += buf[p][t - off][k];
            buf[1 - p][t][k] = x;
        }
        p ^= 1;
    }
    __syncthreads();
    float st[KC], e[KC];
#pragma unroll
    for (int k = 0; k < KC; k++) st[k] = start[s * KC + k];
#pragma unroll
    for (int k = 0; k < KC; k++) e[k] = st[k] + buf[p][t][k] - a[k];  // exclusive cumsum
    float m = e[0];
#pragma unroll
    for (int k = 1; k < KC; k++) m = fmaxf(m, e[k]);
    float sum = 0.f;
#pragma unroll
    for (int k = 0; k < KC; k++) sum += __expf(e[k] - m);
    float l = m + __logf(sum);
#pragma unroll
    for (int k = 0; k < KC; k++)
        w[(size_t)k * NB + b] = (e[k] - l) - lsev[k];

    if (t == NT - 1) {
        float f[KC];
#pragma unroll
        for (int k = 0; k < KC; k++) f[k] = st[k] + buf[p][t][k];
        float m2 = f[0];
#pragma unroll
        for (int k = 1; k < KC; k++) m2 = fmaxf(m2, f[k]);
        float s2 = 0.f;
#pragma unroll
        for (int k = 0; k < KC; k++) s2 += __expf(f[k] - m2);
        float l2 = m2 + __logf(s2);
#pragma unroll
        for (int k = 0; k < KC; k++) fmix[s * KC + k] = f[k] - l2;
    }
}

// ---------------- final combine: out[b,a] = LSE_k(logit8[k,b,a] + w[k,b]) ----------------
__global__ __launch_bounds__(256) void combine_kernel(
    const unsigned char* __restrict__ logits8,  // [K][B][A] fp8 e4m3
    const float* __restrict__ w,                // [K][B]
    float* __restrict__ out)                    // [B][A]
{
    int b  = blockIdx.x * 2 + (threadIdx.x >> 7);
    int a0 = (threadIdx.x & 127) * 8;
    float x[KC][8];
#pragma unroll
    for (int k = 0; k < KC; k++) {
        float wv = w[(size_t)k * NB + b];
        uint2 q = *(const uint2*)(logits8 + ((size_t)k * NB + b) * ACTN + a0);
        floatx2 p01 = unpk_fp8<false>(q.x), p23 = unpk_fp8<true>(q.x);
        floatx2 p45 = unpk_fp8<false>(q.y), p67 = unpk_fp8<true>(q.y);
        x[k][0] = p01.x + wv; x[k][1] = p01.y + wv;
        x[k][2] = p23.x + wv; x[k][3] = p23.y + wv;
        x[k][4] = p45.x + wv; x[k][5] = p45.y + wv;
        x[k][6] = p67.x + wv; x[k][7] = p67.y + wv;
    }
    float* op = out + (size_t)b * ACTN + a0;
#pragma unroll
    for (int j = 0; j < 8; j++) {
        float m = x[0][j];
#pragma unroll
        for (int k = 1; k < KC; k++) m = fmaxf(m, x[k][j]);
        float s = 0.f;
#pragma unroll
        for (int k = 0; k < KC; k++) s += __expf(x[k][j] - m);
        op[j] = m + __logf(s);
    }
}

extern "C" void kernel_launch(void* const* d_in, const int* in_sizes, int n_in,
                              void* d_out, int out_size, void* d_ws, size_t ws_size,
                              hipStream_t stream)
{
    const float* obs     = (const float*)d_in[0];
    const int*   actions = (const int*)d_in[1];
    const float* start   = (const float*)d_in[2];
    const float* W1      = (const float*)d_in[3];
    const float* b1      = (const float*)d_in[4];
    const float* W2      = (const float*)d_in[5];
    const float* b2      = (const float*)d_in[6];
    // d_in[7] = seq_len (compile-time NT)

    char* ws = (char*)d_ws;
    unsigned short* obs_bk  = (unsigned short*)ws; ws += (size_t)NB * DIM * 2;        // 8 MB
    unsigned short* W1bk    = (unsigned short*)ws; ws += (size_t)KC * HID * DIM * 2;  // 4 MB
    unsigned short* W2bk    = (unsigned short*)ws; ws += (size_t)KC * ACTN * HID * 2; // 8 MB
    unsigned short* hbuf    = (unsigned short*)ws; ws += (size_t)KC * NB * HID * 2;   // 64 MB
    unsigned char*  logits8 = (unsigned char*)ws;  ws += (size_t)KC * NB * ACTN;      // 64 MB
    float* wbuf = (float*)ws; ws += (size_t)KC * NB * 4;                              // 256 KB
    float* psum = (float*)ws; ws += (size_t)KC * NB * PB * 4;                         // 2 MB
    float* palp = (float*)ws; ws += (size_t)KC * NB * 4;                              // 256 KB

    float* out  = (float*)d_out;
    float* fmix = out + (size_t)NB * ACTN;

    // 1. fused prep: obs + W1 + W2 -> blocked bf16
    prep_kernel<<<1664, 256, 0, stream>>>(obs, W1, W2, obs_bk, W1bk, W2bk);

    // 2. h = relu(obs @ W1[k] + b1[k]) -> blocked bf16 (zsA=0: obs shared!)
    gemm_blk_kernel<<<dim3(NB / 128, HID / 128, KC), 256, 0, stream>>>(
        obs_bk, W1bk, b1, hbuf, actions, psum, palp,
        NB, HID, DIM,
        0LL, (long long)HID * DIM,
        HID, (long long)NB * HID * 2, 1, 0, 1);

    // 3. logits = h @ W2[k] + b2[k] -> fp8 [K][B][A] + fused exp-sum + gather
    gemm_blk_kernel<<<dim3(NB / 128, ACTN / 128, KC), 256, 0, stream>>>(
        hbuf, W2bk, b2, logits8, actions, psum, palp,
        NB, ACTN, HID,
        (long long)NB * HID, (long long)ACTN * HID,
        ACTN, (long long)NB * ACTN, 0, 1, 0);

    // 4. per-sequence: lse-finish + cumsum scan -> mixture weights + final mixture logprobs
    mix_kernel<<<NS, NT, 0, stream>>>(palp, psum, start, wbuf, fmix);

    // 5. combine over components
    combine_kernel<<<NB / 2, 256, 0, stream>>>(logits8, wbuf, out);
}